// Round 1
// 466.507 us; speedup vs baseline: 1.0168x; 1.0168x over previous
//
#include <hip/hip_runtime.h>
#include <math.h>

#define HID 32
#define HOR 12
#define REP 8    // one replica plane per XCD (MI355X has 8 XCDs)

__device__ __forceinline__ float sigmoidf_(float x) { return 1.0f / (1.0f + expf(-x)); }

// XCC (XCD) id of the executing wave: hwreg 20, bits [3:0]  (HW-verified 0-7 on gfx950)
__device__ __forceinline__ int xcc_id() {
    return __builtin_amdgcn_s_getreg((3 << 11) | 20) & (REP - 1);
}

// per-edge: degR[xcd][src] += w, cntR[xcd][dst] += 1 with WORKGROUP-scope atomics.
// Plane index = XCC id, so every atomic to a given address executes in the SAME
// per-XCD L2 (no cross-XCD line sharing -> no lost updates; planes are 3125
// full 64B lines each). Avoids the 32B-per-atomic memory-side fabric transaction
// that made the agent-scope version write 102 MB. repE records the plane so
// k_fill (possibly on a different XCD) bins each edge into the bucket that
// was actually counted for it.
__global__ void k_deg_cnt(const int* __restrict__ src, const int* __restrict__ dst,
                          const float* __restrict__ w, float* __restrict__ degR,
                          int* __restrict__ cntR, unsigned char* __restrict__ repE,
                          int E, int N) {
    int e = blockIdx.x * 256 + threadIdx.x;
    if (e < E) {
        int rep = xcc_id();
        __hip_atomic_fetch_add(&degR[(size_t)rep * N + src[e]], w[e],
                               __ATOMIC_RELAXED, __HIP_MEMORY_SCOPE_WORKGROUP);
        __hip_atomic_fetch_add(&cntR[(size_t)rep * N + dst[e]], 1,
                               __ATOMIC_RELAXED, __HIP_MEMORY_SCOPE_WORKGROUP);
        repE[e] = (unsigned char)rep;
    }
}

// fold replica planes: dinv[n] = rsqrt(sum_r degR[r][n]); cnt[n] = sum_r cntR[r][n]
__global__ void k_fold(const float* __restrict__ degR, const int* __restrict__ cntR,
                       float* __restrict__ dinv, int* __restrict__ cnt, int N) {
    int n = blockIdx.x * 256 + threadIdx.x;
    if (n >= N) return;
    float s = 0.0f;
    int c = 0;
    #pragma unroll
    for (int r = 0; r < REP; ++r) {
        s += degR[(size_t)r * N + n];   // coalesced per plane
        c += cntR[(size_t)r * N + n];
    }
    dinv[n] = (s > 0.0f) ? rsqrtf(s) : 0.0f;
    cnt[n] = c;
}

// flag = 1 if any h0 element nonzero (lets gather skip the H0 pass when h0==0)
__global__ void k_hflag(const float* __restrict__ h0, int* __restrict__ flag, int total) {
    int i = blockIdx.x * 256 + threadIdx.x;
    float v = (i < total) ? h0[i] : 0.0f;
    if (__ballot(v != 0.0f)) {
        if ((threadIdx.x & 63) == 0) atomicOr(flag, 1);
    }
}

// scan pass A: per-block sums of cnt
__global__ void k_scan_blocksum(const int* __restrict__ cnt, int* __restrict__ bsum, int N) {
    __shared__ int s[256];
    int i = blockIdx.x * 256 + threadIdx.x;
    s[threadIdx.x] = (i < N) ? cnt[i] : 0;
    __syncthreads();
    for (int off = 128; off > 0; off >>= 1) {
        if (threadIdx.x < off) s[threadIdx.x] += s[threadIdx.x + off];
        __syncthreads();
    }
    if (threadIdx.x == 0) bsum[blockIdx.x] = s[0];
}

// scan pass B: exclusive scan of block sums in place (single block; nB <= 256)
__global__ void k_scan_top(int* __restrict__ bsum, int nB) {
    __shared__ int s[256];
    int tid = threadIdx.x;
    int v = (tid < nB) ? bsum[tid] : 0;
    s[tid] = v;
    __syncthreads();
    for (int off = 1; off < 256; off <<= 1) {
        int t = (tid >= off) ? s[tid - off] : 0;
        __syncthreads();
        s[tid] += t;
        __syncthreads();
    }
    if (tid < nB) bsum[tid] = s[tid] - v;  // exclusive
}

// scan pass C: per-node exclusive scan -> rowptr; init per-(node,rep) cursors
__global__ void k_scan_final(const int* __restrict__ cnt, const int* __restrict__ bsum,
                             const int* __restrict__ cntR,
                             int* __restrict__ rowptr, int* __restrict__ cursorR, int N) {
    __shared__ int s[256];
    int tid = threadIdx.x;
    int i = blockIdx.x * 256 + tid;
    int v = (i < N) ? cnt[i] : 0;
    s[tid] = v;
    __syncthreads();
    for (int off = 1; off < 256; off <<= 1) {
        int t = (tid >= off) ? s[tid - off] : 0;
        __syncthreads();
        s[tid] += t;
        __syncthreads();
    }
    int excl = s[tid] - v + bsum[blockIdx.x];
    if (i < N) {
        rowptr[i] = excl;
        int run = excl;
        #pragma unroll
        for (int r = 0; r < REP; ++r) {
            cursorR[(size_t)r * N + i] = run;     // coalesced per plane
            run += cntR[(size_t)r * N + i];
        }
        if (i == N - 1) rowptr[N] = excl + v;
    }
}

// bin edges by dst using the replica recorded in pass 1; pack (src, nw) into int2.
// cursor atomic must stay agent-scope: edges with the same recorded rep may be
// processed on any XCD here.
__global__ void k_fill(const int* __restrict__ src, const int* __restrict__ dst,
                       const float* __restrict__ w, const float* __restrict__ dinv,
                       const unsigned char* __restrict__ repE,
                       int* __restrict__ cursorR, int2* __restrict__ epair, int E, int N) {
    int e = blockIdx.x * 256 + threadIdx.x;
    if (e >= E) return;
    int s = src[e], d = dst[e];
    float nw = -dinv[s] * w[e] * dinv[d];
    int rep = repE[e];
    int p = atomicAdd(&cursorR[(size_t)rep * N + d], 1);
    epair[p] = make_int2(s, __float_as_int(nw));
}

// per dst node (32 lanes = 32 feats): accumulate LX (and LH if hflag) without atomics
__global__ __launch_bounds__(256) void k_gather(const int* __restrict__ rowptr,
                                                const int2* __restrict__ epair,
                                                const float* __restrict__ X,
                                                const float* __restrict__ H0,
                                                const int* __restrict__ hflag,
                                                float* __restrict__ LX, float* __restrict__ LH,
                                                int N) {
    int tid = blockIdx.x * 256 + threadIdx.x;
    int n = tid >> 5;
    int f = tid & 31;
    if (n >= N) return;
    int beg = rowptr[n], end = rowptr[n + 1];
    float acc = 0.0f, accH = 0.0f;
    if (*hflag) {
        #pragma unroll 4
        for (int i = beg; i < end; ++i) {
            int2 p = epair[i];
            float w = __int_as_float(p.y);
            acc  += w * X[(p.x << 5) + f];
            accH += w * H0[(p.x << 5) + f];
        }
    } else {
        #pragma unroll 4
        for (int i = beg; i < end; ++i) {
            int2 p = epair[i];
            acc += __int_as_float(p.y) * X[(p.x << 5) + f];
        }
    }
    LX[(n << 5) + f] = acc;
    LH[(n << 5) + f] = accH;
}

// Per (node n, out-feature j): 4 gates fused LSTM cell
__global__ __launch_bounds__(256) void k_gates(
    const float* __restrict__ X, const float* __restrict__ LX,
    const float* __restrict__ H0, const float* __restrict__ LH,
    const float* __restrict__ C0,
    const float* __restrict__ Wx, const float* __restrict__ bx,
    const float* __restrict__ Wh, const float* __restrict__ bh,
    const float* __restrict__ wc, const float* __restrict__ b,
    float* __restrict__ outH, float* __restrict__ outC, int N) {
    int tid = blockIdx.x * 256 + threadIdx.x;
    int n = tid >> 5;
    int j = tid & 31;
    if (n >= N) return;

    int base = n << 5;
    float xk  = X[base + j];
    float lxk = LX[base + j];
    float hk  = H0[base + j];
    float lhk = LH[base + j];

    float pre0 = bx[0 * HID + j] + bh[0 * HID + j] + b[0 * HID + j];
    float pre1 = bx[1 * HID + j] + bh[1 * HID + j] + b[1 * HID + j];
    float pre2 = bx[2 * HID + j] + bh[2 * HID + j] + b[2 * HID + j];
    float pre3 = bx[3 * HID + j] + bh[3 * HID + j] + b[3 * HID + j];

    #pragma unroll 8
    for (int k = 0; k < HID; ++k) {
        float xv  = __shfl(xk, k, 32);
        float lxv = __shfl(lxk, k, 32);
        float hv  = __shfl(hk, k, 32);
        float lhv = __shfl(lhk, k, 32);
        int row = k * HID + j;
        pre0 += xv * Wx[0 * 2048 + row] + lxv * Wx[0 * 2048 + 1024 + row]
              + hv * Wh[0 * 2048 + row] + lhv * Wh[0 * 2048 + 1024 + row];
        pre1 += xv * Wx[1 * 2048 + row] + lxv * Wx[1 * 2048 + 1024 + row]
              + hv * Wh[1 * 2048 + row] + lhv * Wh[1 * 2048 + 1024 + row];
        pre2 += xv * Wx[2 * 2048 + row] + lxv * Wx[2 * 2048 + 1024 + row]
              + hv * Wh[2 * 2048 + row] + lhv * Wh[2 * 2048 + 1024 + row];
        pre3 += xv * Wx[3 * 2048 + row] + lxv * Wx[3 * 2048 + 1024 + row]
              + hv * Wh[3 * 2048 + row] + lhv * Wh[3 * 2048 + 1024 + row];
    }

    float c0v = C0[base + j];
    float I  = sigmoidf_(pre0 + wc[0 * HID + j] * c0v);
    float Fg = sigmoidf_(pre1 + wc[1 * HID + j] * c0v);
    float T  = tanhf(pre2);
    float C  = Fg * c0v + I * T;
    float O  = sigmoidf_(pre3 + wc[2 * HID + j] * C);
    float H  = O * tanhf(C);

    outH[base + j] = H;
    outC[base + j] = C;
}

// h[n,t] = b_lin[t] + sum_k relu(H[n,k]) * W_lin[k,t]
__global__ void k_head(const float* __restrict__ H, const float* __restrict__ Wl,
                       const float* __restrict__ bl, float* __restrict__ hout, int N) {
    int tid = blockIdx.x * 256 + threadIdx.x;
    int n = tid / HOR;
    int t = tid - n * HOR;
    if (n >= N) return;
    float acc = bl[t];
    #pragma unroll
    for (int k = 0; k < HID; ++k) {
        float v = H[(n << 5) + k];
        acc += fmaxf(v, 0.0f) * Wl[k * HOR + t];
    }
    hout[n * HOR + t] = acc;
}

extern "C" void kernel_launch(void* const* d_in, const int* in_sizes, int n_in,
                              void* d_out, int out_size, void* d_ws, size_t ws_size,
                              hipStream_t stream) {
    const float* x  = (const float*)d_in[0];
    const int*   ei = (const int*)d_in[1];
    const float* ew = (const float*)d_in[2];
    const float* Wx = (const float*)d_in[3];
    const float* bx = (const float*)d_in[4];
    const float* Wh = (const float*)d_in[5];
    const float* bh = (const float*)d_in[6];
    const float* wc = (const float*)d_in[7];
    const float* b  = (const float*)d_in[8];
    const float* Wl = (const float*)d_in[9];
    const float* bl = (const float*)d_in[10];
    const float* h0 = (const float*)d_in[11];
    const float* c0 = (const float*)d_in[12];

    int N = in_sizes[0] / HID;      // x is (N,1,32)
    int E = in_sizes[2];            // edge_weight is (E,)
    const int* src = ei;
    const int* dst = ei + E;
    int nB = (N + 255) / 256;       // 196 for N=50000; must be <= 256

    // workspace (4-byte units). degR/cntR alias epair: both are dead before
    // k_fill writes epair (k_fold consumes degR, k_scan_final consumes cntR).
    // [epair 2E | degR R*N + cntR R*N aliased] [LX N*32] [LH N*32]
    // [rowptr N+1] [cursorR R*N] [bsum 256] [dinv N] [cnt N] [flag 1] [repE E bytes]
    int* wsi = (int*)d_ws;
    int2*  epair  = (int2*)wsi;
    float* degR   = (float*)wsi;                      // R*N, aliases epair
    int*   cntR   = wsi + (size_t)REP * N;            // R*N, aliases epair
    float* LX     = (float*)(wsi + 2 * (size_t)E);
    float* LH     = LX + (size_t)N * HID;
    int*   rowptr = (int*)(LH + (size_t)N * HID);
    int*   cursorR= rowptr + (N + 1);
    int*   bsum   = cursorR + (size_t)REP * N;
    float* dinv   = (float*)(bsum + 256);
    int*   cnt    = (int*)(dinv + N);
    int*   flag   = cnt + N;
    unsigned char* repE = (unsigned char*)(flag + 1); // E bytes, must NOT alias epair

    float* hOut = (float*)d_out;            // (N,12)
    float* HOut = hOut + (size_t)N * HOR;   // (N,32)
    float* COut = HOut + (size_t)N * HID;   // (N,32)

    hipMemsetAsync(degR, 0, 2 * (size_t)REP * N * sizeof(int), stream);  // degR + cntR
    hipMemsetAsync(flag, 0, sizeof(int), stream);

    k_deg_cnt<<<(E + 255) / 256, 256, 0, stream>>>(src, dst, ew, degR, cntR, repE, E, N);
    k_fold<<<(N + 255) / 256, 256, 0, stream>>>(degR, cntR, dinv, cnt, N);
    k_hflag<<<(N * HID + 255) / 256, 256, 0, stream>>>(h0, flag, N * HID);

    k_scan_blocksum<<<nB, 256, 0, stream>>>(cnt, bsum, N);
    k_scan_top<<<1, 256, 0, stream>>>(bsum, nB);
    k_scan_final<<<nB, 256, 0, stream>>>(cnt, bsum, cntR, rowptr, cursorR, N);

    k_fill<<<(E + 255) / 256, 256, 0, stream>>>(src, dst, ew, dinv, repE, cursorR, epair, E, N);

    k_gather<<<(N * HID + 255) / 256, 256, 0, stream>>>(rowptr, epair, x, h0, flag, LX, LH, N);

    k_gates<<<(N * HID + 255) / 256, 256, 0, stream>>>(x, LX, h0, LH, c0,
                                                       Wx, bx, Wh, bh, wc, b,
                                                       HOut, COut, N);

    k_head<<<(N * HOR + 255) / 256, 256, 0, stream>>>(HOut, Wl, bl, hOut, N);
}

// Round 2
// 423.909 us; speedup vs baseline: 1.1190x; 1.1005x over previous
//
#include <hip/hip_runtime.h>
#include <math.h>

#define HID 32
#define HOR 12
#define NB 256   // histogram/scatter blocks; k_offsets does an NB-long sequential prefix

__device__ __forceinline__ float sigmoidf_(float x) { return 1.0f / (1.0f + expf(-x)); }

// ---------------------------------------------------------------------------
// MSD bucket sort by node id (node < 65536 required: N = 50000).
// Level 1: high byte (node>>8) via per-block LDS histograms + global scatter.
// Level 2: low byte, entirely inside one block per high-group. No stability
// needed anywhere: final bins are exact dst values, within-bin order is free.
// All atomics are LDS atomics; every global write is a plain store.
// ---------------------------------------------------------------------------

// per-block histograms of src>>8 and dst>>8
__global__ __launch_bounds__(256) void k_hist(const int* __restrict__ src,
                                              const int* __restrict__ dst,
                                              int* __restrict__ histS, int* __restrict__ histD,
                                              int E, int chunk, int ng) {
    __shared__ int hS[256], hD[256];
    int t = threadIdx.x, b = blockIdx.x;
    hS[t] = 0; hD[t] = 0;
    __syncthreads();
    int beg = b * chunk, end = min(E, beg + chunk);
    for (int e = beg + t; e < end; e += 256) {
        atomicAdd(&hS[src[e] >> 8], 1);
        atomicAdd(&hD[dst[e] >> 8], 1);
    }
    __syncthreads();
    if (t < ng) { histS[b * ng + t] = hS[t]; histD[b * ng + t] = hD[t]; }
}

// single block, 512 threads: lower half handles the src table, upper half dst.
// Produces per-(block,bin) scatter offsets, group bases, and rowptr[N]=E.
__global__ __launch_bounds__(512) void k_offsets(const int* __restrict__ histS,
                                                 const int* __restrict__ histD,
                                                 int* __restrict__ offS, int* __restrict__ offD,
                                                 int* __restrict__ baseS, int* __restrict__ baseD,
                                                 int* __restrict__ rowptr,
                                                 int E, int nb, int ng, int N) {
    __shared__ int buf[512];
    int t = threadIdx.x;
    int lt = t & 255;
    const int* hist = (t < 256) ? histS : histD;
    int sum = 0;
    if (lt < ng) for (int b = 0; b < nb; ++b) sum += hist[b * ng + lt];
    buf[t] = sum;
    __syncthreads();
    for (int off = 1; off < 256; off <<= 1) {       // per-half inclusive scan
        int v = (lt >= off) ? buf[t - off] : 0;
        __syncthreads();
        buf[t] += v;
        __syncthreads();
    }
    int base = buf[t] - sum;                        // exclusive
    if (lt < ng) { if (t < 256) baseS[lt] = base; else baseD[lt] = base; }
    if (t == 0)   { baseS[ng] = E; rowptr[N] = E; }
    if (t == 256) { baseD[ng] = E; }
    if (lt < ng) {
        int* off_ = (t < 256) ? offS : offD;
        int run = base;
        for (int b = 0; b < nb; ++b) { off_[b * ng + lt] = run; run += hist[b * ng + lt]; }
    }
}

// scatter edges into high-byte buckets (both keyings) using LDS cursors.
__global__ __launch_bounds__(256) void k_scatter(const int* __restrict__ src,
                                                 const int* __restrict__ dst,
                                                 const float* __restrict__ w,
                                                 const int* __restrict__ offS,
                                                 const int* __restrict__ offD,
                                                 int2* __restrict__ tmpS, int2* __restrict__ tmpD,
                                                 int E, int chunk, int ng) {
    __shared__ int cS[256], cD[256];
    int t = threadIdx.x, b = blockIdx.x;
    if (t < ng) { cS[t] = offS[b * ng + t]; cD[t] = offD[b * ng + t]; }
    __syncthreads();
    int beg = b * chunk, end = min(E, beg + chunk);
    for (int e = beg + t; e < end; e += 256) {
        int s = src[e], d = dst[e];
        int wb = __float_as_int(w[e]);
        int pS = atomicAdd(&cS[s >> 8], 1);
        tmpS[pS] = make_int2(s, wb);
        int pD = atomicAdd(&cD[d >> 8], 1);
        tmpD[pD] = make_int2(s | ((d & 255) << 16), wb);   // src fits 16 bits (N<=65536)
    }
}

// per src-high-group: LDS float histogram over low byte -> dinv (no global atomics)
__global__ __launch_bounds__(256) void k_degsum(const int2* __restrict__ tmpS,
                                                const int* __restrict__ baseS,
                                                float* __restrict__ dinv, int N) {
    __shared__ float h[256];
    int g = blockIdx.x, t = threadIdx.x;
    h[t] = 0.0f;
    __syncthreads();
    int beg = baseS[g], end = baseS[g + 1];
    for (int i = beg + t; i < end; i += 256) {
        int2 p = tmpS[i];
        atomicAdd(&h[p.x & 255], __int_as_float(p.y));
    }
    __syncthreads();
    int n = (g << 8) + t;
    if (n < N) { float s = h[t]; dinv[n] = (s > 0.0f) ? rsqrtf(s) : 0.0f; }
}

// per dst-high-group: low-byte count + scan -> rowptr; then bin edges to exact
// dst, computing nw now that dinv exists. Within-dst order is arbitrary (sum).
__global__ __launch_bounds__(256) void k_scatter2(const int2* __restrict__ tmpD,
                                                  const int* __restrict__ baseD,
                                                  const float* __restrict__ dinv,
                                                  int* __restrict__ rowptr,
                                                  int2* __restrict__ epair, int N) {
    __shared__ int h[256];
    __shared__ int cur[256];
    int g = blockIdx.x, t = threadIdx.x;
    h[t] = 0;
    __syncthreads();
    int beg = baseD[g], end = baseD[g + 1];
    for (int i = beg + t; i < end; i += 256) atomicAdd(&h[(tmpD[i].x >> 16) & 255], 1);
    __syncthreads();
    int v = h[t];
    for (int off = 1; off < 256; off <<= 1) {
        int x = (t >= off) ? h[t - off] : 0;
        __syncthreads();
        h[t] += x;
        __syncthreads();
    }
    int excl = h[t] - v;
    int n = (g << 8) + t;
    if (n < N) rowptr[n] = beg + excl;
    cur[t] = beg + excl;
    __syncthreads();
    for (int i = beg + t; i < end; i += 256) {
        int2 p = tmpD[i];
        int low = (p.x >> 16) & 255;
        int s = p.x & 0xFFFF;
        int pos = atomicAdd(&cur[low], 1);
        float nw = -dinv[s] * __int_as_float(p.y) * dinv[(g << 8) + low];
        epair[pos] = make_int2(s, __float_as_int(nw));
    }
}

// flag = 1 if any h0 element nonzero (lets gather skip the H0 pass when h0==0)
__global__ void k_hflag(const float* __restrict__ h0, int* __restrict__ flag, int total) {
    int i = blockIdx.x * 256 + threadIdx.x;
    float v = (i < total) ? h0[i] : 0.0f;
    if (__ballot(v != 0.0f)) {
        if ((threadIdx.x & 63) == 0) atomicOr(flag, 1);
    }
}

// per dst node (32 lanes = 32 feats): accumulate LX (and LH if hflag) without atomics
__global__ __launch_bounds__(256) void k_gather(const int* __restrict__ rowptr,
                                                const int2* __restrict__ epair,
                                                const float* __restrict__ X,
                                                const float* __restrict__ H0,
                                                const int* __restrict__ hflag,
                                                float* __restrict__ LX, float* __restrict__ LH,
                                                int N) {
    int tid = blockIdx.x * 256 + threadIdx.x;
    int n = tid >> 5;
    int f = tid & 31;
    if (n >= N) return;
    int beg = rowptr[n], end = rowptr[n + 1];
    float acc = 0.0f, accH = 0.0f;
    if (*hflag) {
        #pragma unroll 4
        for (int i = beg; i < end; ++i) {
            int2 p = epair[i];
            float w = __int_as_float(p.y);
            acc  += w * X[(p.x << 5) + f];
            accH += w * H0[(p.x << 5) + f];
        }
    } else {
        #pragma unroll 4
        for (int i = beg; i < end; ++i) {
            int2 p = epair[i];
            acc += __int_as_float(p.y) * X[(p.x << 5) + f];
        }
    }
    LX[(n << 5) + f] = acc;
    LH[(n << 5) + f] = accH;
}

// Per (node n, out-feature j): 4 gates fused LSTM cell
__global__ __launch_bounds__(256) void k_gates(
    const float* __restrict__ X, const float* __restrict__ LX,
    const float* __restrict__ H0, const float* __restrict__ LH,
    const float* __restrict__ C0,
    const float* __restrict__ Wx, const float* __restrict__ bx,
    const float* __restrict__ Wh, const float* __restrict__ bh,
    const float* __restrict__ wc, const float* __restrict__ b,
    float* __restrict__ outH, float* __restrict__ outC, int N) {
    int tid = blockIdx.x * 256 + threadIdx.x;
    int n = tid >> 5;
    int j = tid & 31;
    if (n >= N) return;

    int base = n << 5;
    float xk  = X[base + j];
    float lxk = LX[base + j];
    float hk  = H0[base + j];
    float lhk = LH[base + j];

    float pre0 = bx[0 * HID + j] + bh[0 * HID + j] + b[0 * HID + j];
    float pre1 = bx[1 * HID + j] + bh[1 * HID + j] + b[1 * HID + j];
    float pre2 = bx[2 * HID + j] + bh[2 * HID + j] + b[2 * HID + j];
    float pre3 = bx[3 * HID + j] + bh[3 * HID + j] + b[3 * HID + j];

    #pragma unroll 8
    for (int k = 0; k < HID; ++k) {
        float xv  = __shfl(xk, k, 32);
        float lxv = __shfl(lxk, k, 32);
        float hv  = __shfl(hk, k, 32);
        float lhv = __shfl(lhk, k, 32);
        int row = k * HID + j;
        pre0 += xv * Wx[0 * 2048 + row] + lxv * Wx[0 * 2048 + 1024 + row]
              + hv * Wh[0 * 2048 + row] + lhv * Wh[0 * 2048 + 1024 + row];
        pre1 += xv * Wx[1 * 2048 + row] + lxv * Wx[1 * 2048 + 1024 + row]
              + hv * Wh[1 * 2048 + row] + lhv * Wh[1 * 2048 + 1024 + row];
        pre2 += xv * Wx[2 * 2048 + row] + lxv * Wx[2 * 2048 + 1024 + row]
              + hv * Wh[2 * 2048 + row] + lhv * Wh[2 * 2048 + 1024 + row];
        pre3 += xv * Wx[3 * 2048 + row] + lxv * Wx[3 * 2048 + 1024 + row]
              + hv * Wh[3 * 2048 + row] + lhv * Wh[3 * 2048 + 1024 + row];
    }

    float c0v = C0[base + j];
    float I  = sigmoidf_(pre0 + wc[0 * HID + j] * c0v);
    float Fg = sigmoidf_(pre1 + wc[1 * HID + j] * c0v);
    float T  = tanhf(pre2);
    float C  = Fg * c0v + I * T;
    float O  = sigmoidf_(pre3 + wc[2 * HID + j] * C);
    float H  = O * tanhf(C);

    outH[base + j] = H;
    outC[base + j] = C;
}

// h[n,t] = b_lin[t] + sum_k relu(H[n,k]) * W_lin[k,t]
__global__ void k_head(const float* __restrict__ H, const float* __restrict__ Wl,
                       const float* __restrict__ bl, float* __restrict__ hout, int N) {
    int tid = blockIdx.x * 256 + threadIdx.x;
    int n = tid / HOR;
    int t = tid - n * HOR;
    if (n >= N) return;
    float acc = bl[t];
    #pragma unroll
    for (int k = 0; k < HID; ++k) {
        float v = H[(n << 5) + k];
        acc += fmaxf(v, 0.0f) * Wl[k * HOR + t];
    }
    hout[n * HOR + t] = acc;
}

extern "C" void kernel_launch(void* const* d_in, const int* in_sizes, int n_in,
                              void* d_out, int out_size, void* d_ws, size_t ws_size,
                              hipStream_t stream) {
    const float* x  = (const float*)d_in[0];
    const int*   ei = (const int*)d_in[1];
    const float* ew = (const float*)d_in[2];
    const float* Wx = (const float*)d_in[3];
    const float* bx = (const float*)d_in[4];
    const float* Wh = (const float*)d_in[5];
    const float* bh = (const float*)d_in[6];
    const float* wc = (const float*)d_in[7];
    const float* b  = (const float*)d_in[8];
    const float* Wl = (const float*)d_in[9];
    const float* bl = (const float*)d_in[10];
    const float* h0 = (const float*)d_in[11];
    const float* c0 = (const float*)d_in[12];

    int N = in_sizes[0] / HID;      // x is (N,1,32)
    int E = in_sizes[2];            // edge_weight is (E,)
    const int* src = ei;
    const int* dst = ei + E;

    int ng = (N + 255) >> 8;        // 196 high-byte groups (N <= 65536 required)
    int chunk = (E + NB - 1) / NB;  // edges per hist/scatter block

    // workspace (4-byte units):
    // [tmpD 2E] [tmpS 2E (aliased by epair)] [LX N*32] [LH N*32] [rowptr N+1]
    // [histS NB*256] [histD NB*256] [offS NB*256] [offD NB*256]
    // [baseS 257] [baseD 257] [dinv N] [flag 1]
    // tmpS is dead after k_degsum, so k_scatter2 may overwrite it with epair.
    int* wsi = (int*)d_ws;
    int2*  tmpD   = (int2*)wsi;
    int2*  tmpS   = (int2*)(wsi + 2 * (size_t)E);
    int2*  epair  = tmpS;                                // alias (see above)
    float* LX     = (float*)(wsi + 4 * (size_t)E);
    float* LH     = LX + (size_t)N * HID;
    int*   rowptr = (int*)(LH + (size_t)N * HID);
    int*   histS  = rowptr + (N + 1);
    int*   histD  = histS + NB * 256;
    int*   offS   = histD + NB * 256;
    int*   offD   = offS + NB * 256;
    int*   baseS  = offD + NB * 256;
    int*   baseD  = baseS + 257;
    float* dinv   = (float*)(baseD + 257);
    int*   flag   = (int*)(dinv + N);

    float* hOut = (float*)d_out;            // (N,12)
    float* HOut = hOut + (size_t)N * HOR;   // (N,32)
    float* COut = HOut + (size_t)N * HID;   // (N,32)

    hipMemsetAsync(flag, 0, sizeof(int), stream);

    k_hist<<<NB, 256, 0, stream>>>(src, dst, histS, histD, E, chunk, ng);
    k_offsets<<<1, 512, 0, stream>>>(histS, histD, offS, offD, baseS, baseD, rowptr, E, NB, ng, N);
    k_scatter<<<NB, 256, 0, stream>>>(src, dst, ew, offS, offD, tmpS, tmpD, E, chunk, ng);
    k_degsum<<<ng, 256, 0, stream>>>(tmpS, baseS, dinv, N);
    k_hflag<<<(N * HID + 255) / 256, 256, 0, stream>>>(h0, flag, N * HID);
    k_scatter2<<<ng, 256, 0, stream>>>(tmpD, baseD, dinv, rowptr, epair, N);

    k_gather<<<(N * HID + 255) / 256, 256, 0, stream>>>(rowptr, epair, x, h0, flag, LX, LH, N);

    k_gates<<<(N * HID + 255) / 256, 256, 0, stream>>>(x, LX, h0, LH, c0,
                                                       Wx, bx, Wh, bh, wc, b,
                                                       HOut, COut, N);

    k_head<<<(N * HOR + 255) / 256, 256, 0, stream>>>(HOut, Wl, bl, hOut, N);
}

// Round 3
// 309.637 us; speedup vs baseline: 1.5320x; 1.3691x over previous
//
#include <hip/hip_runtime.h>
#include <math.h>

#define HID 32
#define HOR 12
#define NB 256   // histogram/scatter blocks (must equal blockDim of k_binscan)
#define NPT 8    // nodes per thread in k_gates (weight loads amortized 8x)

__device__ __forceinline__ float sigmoidf_(float x) { return 1.0f / (1.0f + expf(-x)); }

// ---------------------------------------------------------------------------
// MSD bucket sort by node id (node < 65536 required: N = 50000).
// Level 1: high byte (node>>8) via per-block LDS histograms + global scatter.
// Level 2: low byte, entirely inside one block per high-group.
// All atomics are LDS atomics; every global write is a plain store.
// hist layout is BIN-MAJOR: hist[bin2*NB + block], bin2 in [0, 2*ng)
// (S bins first, then D bins) so the per-bin scan is coalesced+parallel.
// ---------------------------------------------------------------------------

// per-block histograms of src>>8 and dst>>8, written bin-major
__global__ __launch_bounds__(256) void k_hist(const int* __restrict__ src,
                                              const int* __restrict__ dst,
                                              int* __restrict__ hist,
                                              int E, int chunk, int ng) {
    __shared__ int hS[256], hD[256];
    int t = threadIdx.x, b = blockIdx.x;
    hS[t] = 0; hD[t] = 0;
    __syncthreads();
    int beg = b * chunk, end = min(E, beg + chunk);
    for (int e = beg + t; e < end; e += 256) {
        atomicAdd(&hS[src[e] >> 8], 1);
        atomicAdd(&hD[dst[e] >> 8], 1);
    }
    __syncthreads();
    if (t < ng) {
        hist[(size_t)t * NB + b] = hS[t];               // S bins: [0, ng)
        hist[((size_t)ng + t) * NB + b] = hD[t];        // D bins: [ng, 2ng)
    }
}

// per-bin exclusive scan across the NB blocks (one block per bin, coalesced)
__global__ __launch_bounds__(256) void k_binscan(const int* __restrict__ hist,
                                                 int* __restrict__ off,
                                                 int* __restrict__ binTot, int ng) {
    __shared__ int s[256];
    int b2 = blockIdx.x, t = threadIdx.x;
    int v = hist[(size_t)b2 * NB + t];
    s[t] = v;
    __syncthreads();
    for (int o = 1; o < 256; o <<= 1) {
        int x = (t >= o) ? s[t - o] : 0;
        __syncthreads();
        s[t] += x;
        __syncthreads();
    }
    off[(size_t)b2 * NB + t] = s[t] - v;                // within-bin exclusive
    if (t == 255) {
        int idx = (b2 < ng) ? b2 : 256 + (b2 - ng);     // [0,256)=S, [256,512)=D
        binTot[idx] = s[255];
    }
}

// single small block: scan bin totals -> group bases; set sentinels.
__global__ __launch_bounds__(512) void k_binbase(const int* __restrict__ binTot,
                                                 int* __restrict__ baseS, int* __restrict__ baseD,
                                                 int* __restrict__ rowptr,
                                                 int E, int ng, int N) {
    __shared__ int buf[512];
    int t = threadIdx.x;
    int lt = t & 255;
    int sum = (lt < ng) ? binTot[(t < 256 ? 0 : 256) + lt] : 0;
    buf[t] = sum;
    __syncthreads();
    for (int o = 1; o < 256; o <<= 1) {                 // per-half inclusive scan
        int v = (lt >= o) ? buf[t - o] : 0;
        __syncthreads();
        buf[t] += v;
        __syncthreads();
    }
    int base = buf[t] - sum;                            // exclusive
    if (lt < ng) { if (t < 256) baseS[lt] = base; else baseD[lt] = base; }
    if (t == 0)   { baseS[ng] = E; rowptr[N] = E; }
    if (t == 256) { baseD[ng] = E; }
}

// scatter edges into high-byte buckets (both keyings) using LDS cursors.
__global__ __launch_bounds__(256) void k_scatter(const int* __restrict__ src,
                                                 const int* __restrict__ dst,
                                                 const float* __restrict__ w,
                                                 const int* __restrict__ off,
                                                 const int* __restrict__ baseS,
                                                 const int* __restrict__ baseD,
                                                 int2* __restrict__ tmpS, int2* __restrict__ tmpD,
                                                 int E, int chunk, int ng) {
    __shared__ int cS[256], cD[256];
    int t = threadIdx.x, b = blockIdx.x;
    if (t < ng) {
        cS[t] = off[(size_t)t * NB + b] + baseS[t];
        cD[t] = off[((size_t)ng + t) * NB + b] + baseD[t];
    }
    __syncthreads();
    int beg = b * chunk, end = min(E, beg + chunk);
    for (int e = beg + t; e < end; e += 256) {
        int s = src[e], d = dst[e];
        int wb = __float_as_int(w[e]);
        int pS = atomicAdd(&cS[s >> 8], 1);
        tmpS[pS] = make_int2(s, wb);
        int pD = atomicAdd(&cD[d >> 8], 1);
        tmpD[pD] = make_int2(s | ((d & 255) << 16), wb);   // src fits 16 bits (N<=65536)
    }
}

// per src-high-group: LDS float histogram over low byte -> dinv (no global atomics)
__global__ __launch_bounds__(256) void k_degsum(const int2* __restrict__ tmpS,
                                                const int* __restrict__ baseS,
                                                float* __restrict__ dinv, int N) {
    __shared__ float h[256];
    int g = blockIdx.x, t = threadIdx.x;
    h[t] = 0.0f;
    __syncthreads();
    int beg = baseS[g], end = baseS[g + 1];
    for (int i = beg + t; i < end; i += 256) {
        int2 p = tmpS[i];
        atomicAdd(&h[p.x & 255], __int_as_float(p.y));
    }
    __syncthreads();
    int n = (g << 8) + t;
    if (n < N) { float s = h[t]; dinv[n] = (s > 0.0f) ? rsqrtf(s) : 0.0f; }
}

// per dst-high-group: low-byte count + scan -> rowptr; then bin edges to exact
// dst, computing nw now that dinv exists. Within-dst order is arbitrary (sum).
__global__ __launch_bounds__(256) void k_scatter2(const int2* __restrict__ tmpD,
                                                  const int* __restrict__ baseD,
                                                  const float* __restrict__ dinv,
                                                  int* __restrict__ rowptr,
                                                  int2* __restrict__ epair, int N) {
    __shared__ int h[256];
    __shared__ int cur[256];
    int g = blockIdx.x, t = threadIdx.x;
    h[t] = 0;
    __syncthreads();
    int beg = baseD[g], end = baseD[g + 1];
    for (int i = beg + t; i < end; i += 256) atomicAdd(&h[(tmpD[i].x >> 16) & 255], 1);
    __syncthreads();
    int v = h[t];
    for (int off = 1; off < 256; off <<= 1) {
        int x = (t >= off) ? h[t - off] : 0;
        __syncthreads();
        h[t] += x;
        __syncthreads();
    }
    int excl = h[t] - v;
    int n = (g << 8) + t;
    if (n < N) rowptr[n] = beg + excl;
    cur[t] = beg + excl;
    __syncthreads();
    for (int i = beg + t; i < end; i += 256) {
        int2 p = tmpD[i];
        int low = (p.x >> 16) & 255;
        int s = p.x & 0xFFFF;
        int pos = atomicAdd(&cur[low], 1);
        float nw = -dinv[s] * __int_as_float(p.y) * dinv[(g << 8) + low];
        epair[pos] = make_int2(s, __float_as_int(nw));
    }
}

// flag = 1 if any h0 element nonzero (lets gather skip the H0 pass when h0==0)
__global__ void k_hflag(const float* __restrict__ h0, int* __restrict__ flag, int total) {
    int i = blockIdx.x * 256 + threadIdx.x;
    float v = (i < total) ? h0[i] : 0.0f;
    if (__ballot(v != 0.0f)) {
        if ((threadIdx.x & 63) == 0) atomicOr(flag, 1);
    }
}

// per dst node (32 lanes = 32 feats): accumulate LX (and LH if hflag) without atomics
__global__ __launch_bounds__(256) void k_gather(const int* __restrict__ rowptr,
                                                const int2* __restrict__ epair,
                                                const float* __restrict__ X,
                                                const float* __restrict__ H0,
                                                const int* __restrict__ hflag,
                                                float* __restrict__ LX, float* __restrict__ LH,
                                                int N) {
    int tid = blockIdx.x * 256 + threadIdx.x;
    int n = tid >> 5;
    int f = tid & 31;
    if (n >= N) return;
    int beg = rowptr[n], end = rowptr[n + 1];
    float acc = 0.0f, accH = 0.0f;
    if (*hflag) {
        #pragma unroll 4
        for (int i = beg; i < end; ++i) {
            int2 p = epair[i];
            float w = __int_as_float(p.y);
            acc  += w * X[(p.x << 5) + f];
            accH += w * H0[(p.x << 5) + f];
        }
    } else {
        #pragma unroll 4
        for (int i = beg; i < end; ++i) {
            int2 p = epair[i];
            acc += __int_as_float(p.y) * X[(p.x << 5) + f];
        }
    }
    LX[(n << 5) + f] = acc;
    LH[(n << 5) + f] = accH;
}

// Per (node-group g of NPT nodes, out-feature j): 4-gate fused LSTM cell.
// Weight loads are shared by NPT nodes -> 16 loads per 16*NPT FMAs.
__global__ __launch_bounds__(256) void k_gates(
    const float* __restrict__ X, const float* __restrict__ LX,
    const float* __restrict__ H0, const float* __restrict__ LH,
    const float* __restrict__ C0,
    const float* __restrict__ Wx, const float* __restrict__ bx,
    const float* __restrict__ Wh, const float* __restrict__ bh,
    const float* __restrict__ wc, const float* __restrict__ b,
    float* __restrict__ outH, float* __restrict__ outC, int N) {
    int tid = blockIdx.x * 256 + threadIdx.x;
    int g = tid >> 5;           // node group
    int j = tid & 31;           // output feature
    int n0 = g * NPT;
    if (n0 >= N) return;
    int cnt = min(NPT, N - n0);

    float xk[NPT], lxk[NPT], hk[NPT], lhk[NPT];
    #pragma unroll
    for (int i = 0; i < NPT; ++i) { xk[i] = 0.0f; lxk[i] = 0.0f; hk[i] = 0.0f; lhk[i] = 0.0f; }
    for (int i = 0; i < cnt; ++i) {
        int base = (n0 + i) << 5;
        xk[i]  = X[base + j];
        lxk[i] = LX[base + j];
        hk[i]  = H0[base + j];
        lhk[i] = LH[base + j];
    }

    float pre[4][NPT];
    #pragma unroll
    for (int gt = 0; gt < 4; ++gt) {
        float bb = bx[gt * HID + j] + bh[gt * HID + j] + b[gt * HID + j];
        #pragma unroll
        for (int i = 0; i < NPT; ++i) pre[gt][i] = bb;
    }

    #pragma unroll 2
    for (int k = 0; k < HID; ++k) {
        float w0[4], w1[4], w2[4], w3[4];
        int row = k * HID + j;
        #pragma unroll
        for (int gt = 0; gt < 4; ++gt) {
            w0[gt] = Wx[gt * 2048 + row];
            w1[gt] = Wx[gt * 2048 + 1024 + row];
            w2[gt] = Wh[gt * 2048 + row];
            w3[gt] = Wh[gt * 2048 + 1024 + row];
        }
        #pragma unroll
        for (int i = 0; i < NPT; ++i) {
            float xv  = __shfl(xk[i],  k, 32);
            float lxv = __shfl(lxk[i], k, 32);
            float hv  = __shfl(hk[i],  k, 32);
            float lhv = __shfl(lhk[i], k, 32);
            #pragma unroll
            for (int gt = 0; gt < 4; ++gt)
                pre[gt][i] += xv * w0[gt] + lxv * w1[gt] + hv * w2[gt] + lhv * w3[gt];
        }
    }

    float wc0 = wc[0 * HID + j], wc1 = wc[1 * HID + j], wc2 = wc[2 * HID + j];
    for (int i = 0; i < cnt; ++i) {
        int base = (n0 + i) << 5;
        float c0v = C0[base + j];
        float I  = sigmoidf_(pre[0][i] + wc0 * c0v);
        float Fg = sigmoidf_(pre[1][i] + wc1 * c0v);
        float T  = tanhf(pre[2][i]);
        float C  = Fg * c0v + I * T;
        float O  = sigmoidf_(pre[3][i] + wc2 * C);
        float H  = O * tanhf(C);
        outH[base + j] = H;
        outC[base + j] = C;
    }
}

// h[n,t] = b_lin[t] + sum_k relu(H[n,k]) * W_lin[k,t]
__global__ void k_head(const float* __restrict__ H, const float* __restrict__ Wl,
                       const float* __restrict__ bl, float* __restrict__ hout, int N) {
    int tid = blockIdx.x * 256 + threadIdx.x;
    int n = tid / HOR;
    int t = tid - n * HOR;
    if (n >= N) return;
    float acc = bl[t];
    #pragma unroll
    for (int k = 0; k < HID; ++k) {
        float v = H[(n << 5) + k];
        acc += fmaxf(v, 0.0f) * Wl[k * HOR + t];
    }
    hout[n * HOR + t] = acc;
}

extern "C" void kernel_launch(void* const* d_in, const int* in_sizes, int n_in,
                              void* d_out, int out_size, void* d_ws, size_t ws_size,
                              hipStream_t stream) {
    const float* x  = (const float*)d_in[0];
    const int*   ei = (const int*)d_in[1];
    const float* ew = (const float*)d_in[2];
    const float* Wx = (const float*)d_in[3];
    const float* bx = (const float*)d_in[4];
    const float* Wh = (const float*)d_in[5];
    const float* bh = (const float*)d_in[6];
    const float* wc = (const float*)d_in[7];
    const float* b  = (const float*)d_in[8];
    const float* Wl = (const float*)d_in[9];
    const float* bl = (const float*)d_in[10];
    const float* h0 = (const float*)d_in[11];
    const float* c0 = (const float*)d_in[12];

    int N = in_sizes[0] / HID;      // x is (N,1,32)
    int E = in_sizes[2];            // edge_weight is (E,)
    const int* src = ei;
    const int* dst = ei + E;

    int ng = (N + 255) >> 8;        // 196 high-byte groups (N <= 65536 required)
    int chunk = (E + NB - 1) / NB;  // edges per hist/scatter block

    // workspace (4-byte units):
    // [tmpD 2E] [tmpS 2E (aliased by epair)] [LX N*32] [LH N*32] [rowptr N+1]
    // [hist 2*ng*NB] [off 2*ng*NB] [binTot 512] [baseS 257] [baseD 257] [dinv N] [flag 1]
    // tmpS is dead after k_degsum, so k_scatter2 may overwrite it with epair.
    int* wsi = (int*)d_ws;
    int2*  tmpD   = (int2*)wsi;
    int2*  tmpS   = (int2*)(wsi + 2 * (size_t)E);
    int2*  epair  = tmpS;                                // alias (see above)
    float* LX     = (float*)(wsi + 4 * (size_t)E);
    float* LH     = LX + (size_t)N * HID;
    int*   rowptr = (int*)(LH + (size_t)N * HID);
    int*   hist   = rowptr + (N + 1);
    int*   off    = hist + 2 * (size_t)ng * NB;
    int*   binTot = off + 2 * (size_t)ng * NB;
    int*   baseS  = binTot + 512;
    int*   baseD  = baseS + 257;
    float* dinv   = (float*)(baseD + 257);
    int*   flag   = (int*)(dinv + N);

    float* hOut = (float*)d_out;            // (N,12)
    float* HOut = hOut + (size_t)N * HOR;   // (N,32)
    float* COut = HOut + (size_t)N * HID;   // (N,32)

    hipMemsetAsync(flag, 0, sizeof(int), stream);

    k_hist<<<NB, 256, 0, stream>>>(src, dst, hist, E, chunk, ng);
    k_binscan<<<2 * ng, 256, 0, stream>>>(hist, off, binTot, ng);
    k_binbase<<<1, 512, 0, stream>>>(binTot, baseS, baseD, rowptr, E, ng, N);
    k_scatter<<<NB, 256, 0, stream>>>(src, dst, ew, off, baseS, baseD, tmpS, tmpD, E, chunk, ng);
    k_degsum<<<ng, 256, 0, stream>>>(tmpS, baseS, dinv, N);
    k_hflag<<<(N * HID + 255) / 256, 256, 0, stream>>>(h0, flag, N * HID);
    k_scatter2<<<ng, 256, 0, stream>>>(tmpD, baseD, dinv, rowptr, epair, N);

    k_gather<<<(N * HID + 255) / 256, 256, 0, stream>>>(rowptr, epair, x, h0, flag, LX, LH, N);

    int gThreads = ((N + NPT - 1) / NPT) * 32;
    k_gates<<<(gThreads + 255) / 256, 256, 0, stream>>>(x, LX, h0, LH, c0,
                                                        Wx, bx, Wh, bh, wc, b,
                                                        HOut, COut, N);

    k_head<<<(N * HOR + 255) / 256, 256, 0, stream>>>(HOut, Wl, bl, hOut, N);
}

// Round 4
// 278.370 us; speedup vs baseline: 1.7040x; 1.1123x over previous
//
#include <hip/hip_runtime.h>
#include <math.h>

#define HID 32
#define HOR 12
#define NB 256   // histogram/scatter blocks (must equal blockDim of k_binscan)
#define NPT 4    // nodes per thread in k_gates

__device__ __forceinline__ float sigmoidf_(float x) { return 1.0f / (1.0f + expf(-x)); }

// ---------------------------------------------------------------------------
// MSD bucket sort by node id (node < 65536 required: N = 50000).
// Level 1: high byte (node>>8) via per-block LDS histograms + global scatter.
// Level 2: low byte, entirely inside one block per high-group.
// All atomics are LDS atomics; every global write is a plain store.
// hist layout is BIN-MAJOR: hist[bin2*NB + block], bin2 in [0, 2*ng)
// (S bins first, then D bins) so the per-bin scan is coalesced+parallel.
// ---------------------------------------------------------------------------

// per-block histograms of src>>8 and dst>>8, written bin-major
__global__ __launch_bounds__(256) void k_hist(const int* __restrict__ src,
                                              const int* __restrict__ dst,
                                              int* __restrict__ hist,
                                              int E, int chunk, int ng) {
    __shared__ int hS[256], hD[256];
    int t = threadIdx.x, b = blockIdx.x;
    hS[t] = 0; hD[t] = 0;
    __syncthreads();
    int beg = b * chunk, end = min(E, beg + chunk);
    for (int e = beg + t; e < end; e += 256) {
        atomicAdd(&hS[src[e] >> 8], 1);
        atomicAdd(&hD[dst[e] >> 8], 1);
    }
    __syncthreads();
    if (t < ng) {
        hist[(size_t)t * NB + b] = hS[t];               // S bins: [0, ng)
        hist[((size_t)ng + t) * NB + b] = hD[t];        // D bins: [ng, 2ng)
    }
}

// per-bin exclusive scan across the NB blocks (one block per bin, coalesced)
__global__ __launch_bounds__(256) void k_binscan(const int* __restrict__ hist,
                                                 int* __restrict__ off,
                                                 int* __restrict__ binTot, int ng) {
    __shared__ int s[256];
    int b2 = blockIdx.x, t = threadIdx.x;
    int v = hist[(size_t)b2 * NB + t];
    s[t] = v;
    __syncthreads();
    for (int o = 1; o < 256; o <<= 1) {
        int x = (t >= o) ? s[t - o] : 0;
        __syncthreads();
        s[t] += x;
        __syncthreads();
    }
    off[(size_t)b2 * NB + t] = s[t] - v;                // within-bin exclusive
    if (t == 255) {
        int idx = (b2 < ng) ? b2 : 256 + (b2 - ng);     // [0,256)=S, [256,512)=D
        binTot[idx] = s[255];
    }
}

// single small block: scan bin totals -> group bases; set sentinels.
__global__ __launch_bounds__(512) void k_binbase(const int* __restrict__ binTot,
                                                 int* __restrict__ baseS, int* __restrict__ baseD,
                                                 int* __restrict__ rowptr,
                                                 int E, int ng, int N) {
    __shared__ int buf[512];
    int t = threadIdx.x;
    int lt = t & 255;
    int sum = (lt < ng) ? binTot[(t < 256 ? 0 : 256) + lt] : 0;
    buf[t] = sum;
    __syncthreads();
    for (int o = 1; o < 256; o <<= 1) {                 // per-half inclusive scan
        int v = (lt >= o) ? buf[t - o] : 0;
        __syncthreads();
        buf[t] += v;
        __syncthreads();
    }
    int base = buf[t] - sum;                            // exclusive
    if (lt < ng) { if (t < 256) baseS[lt] = base; else baseD[lt] = base; }
    if (t == 0)   { baseS[ng] = E; rowptr[N] = E; }
    if (t == 256) { baseD[ng] = E; }
}

// scatter edges into high-byte buckets (both keyings) using LDS cursors.
__global__ __launch_bounds__(256) void k_scatter(const int* __restrict__ src,
                                                 const int* __restrict__ dst,
                                                 const float* __restrict__ w,
                                                 const int* __restrict__ off,
                                                 const int* __restrict__ baseS,
                                                 const int* __restrict__ baseD,
                                                 int2* __restrict__ tmpS, int2* __restrict__ tmpD,
                                                 int E, int chunk, int ng) {
    __shared__ int cS[256], cD[256];
    int t = threadIdx.x, b = blockIdx.x;
    if (t < ng) {
        cS[t] = off[(size_t)t * NB + b] + baseS[t];
        cD[t] = off[((size_t)ng + t) * NB + b] + baseD[t];
    }
    __syncthreads();
    int beg = b * chunk, end = min(E, beg + chunk);
    for (int e = beg + t; e < end; e += 256) {
        int s = src[e], d = dst[e];
        int wb = __float_as_int(w[e]);
        int pS = atomicAdd(&cS[s >> 8], 1);
        tmpS[pS] = make_int2(s, wb);
        int pD = atomicAdd(&cD[d >> 8], 1);
        tmpD[pD] = make_int2(s | ((d & 255) << 16), wb);   // src fits 16 bits (N<=65536)
    }
}

// per src-high-group: LDS float histogram over low byte -> dinv (no global atomics)
__global__ __launch_bounds__(256) void k_degsum(const int2* __restrict__ tmpS,
                                                const int* __restrict__ baseS,
                                                float* __restrict__ dinv, int N) {
    __shared__ float h[256];
    int g = blockIdx.x, t = threadIdx.x;
    h[t] = 0.0f;
    __syncthreads();
    int beg = baseS[g], end = baseS[g + 1];
    for (int i = beg + t; i < end; i += 256) {
        int2 p = tmpS[i];
        atomicAdd(&h[p.x & 255], __int_as_float(p.y));
    }
    __syncthreads();
    int n = (g << 8) + t;
    if (n < N) { float s = h[t]; dinv[n] = (s > 0.0f) ? rsqrtf(s) : 0.0f; }
}

// per dst-high-group: low-byte count + scan -> rowptr; then bin edges to exact
// dst, computing nw now that dinv exists. Within-dst order is arbitrary (sum).
__global__ __launch_bounds__(256) void k_scatter2(const int2* __restrict__ tmpD,
                                                  const int* __restrict__ baseD,
                                                  const float* __restrict__ dinv,
                                                  int* __restrict__ rowptr,
                                                  int2* __restrict__ epair, int N) {
    __shared__ int h[256];
    __shared__ int cur[256];
    int g = blockIdx.x, t = threadIdx.x;
    h[t] = 0;
    __syncthreads();
    int beg = baseD[g], end = baseD[g + 1];
    for (int i = beg + t; i < end; i += 256) atomicAdd(&h[(tmpD[i].x >> 16) & 255], 1);
    __syncthreads();
    int v = h[t];
    for (int off = 1; off < 256; off <<= 1) {
        int x = (t >= off) ? h[t - off] : 0;
        __syncthreads();
        h[t] += x;
        __syncthreads();
    }
    int excl = h[t] - v;
    int n = (g << 8) + t;
    if (n < N) rowptr[n] = beg + excl;
    cur[t] = beg + excl;
    __syncthreads();
    for (int i = beg + t; i < end; i += 256) {
        int2 p = tmpD[i];
        int low = (p.x >> 16) & 255;
        int s = p.x & 0xFFFF;
        int pos = atomicAdd(&cur[low], 1);
        float nw = -dinv[s] * __int_as_float(p.y) * dinv[(g << 8) + low];
        epair[pos] = make_int2(s, __float_as_int(nw));
    }
}

// flag bit0 = any h0 nonzero, bit1 = any c0 nonzero
__global__ void k_flags(const float* __restrict__ h0, const float* __restrict__ c0,
                        int* __restrict__ flag, int total) {
    int i = blockIdx.x * 256 + threadIdx.x;
    float a = (i < total) ? h0[i] : 0.0f;
    float c = (i < total) ? c0[i] : 0.0f;
    unsigned long long ba = __ballot(a != 0.0f);
    unsigned long long bc = __ballot(c != 0.0f);
    if ((threadIdx.x & 63) == 0) {
        int m = (ba ? 1 : 0) | (bc ? 2 : 0);
        if (m) atomicOr(flag, m);
    }
}

// per dst node (32 lanes = 32 feats): accumulate LX (and LH if h0 nonzero)
__global__ __launch_bounds__(256) void k_gather(const int* __restrict__ rowptr,
                                                const int2* __restrict__ epair,
                                                const float* __restrict__ X,
                                                const float* __restrict__ H0,
                                                const int* __restrict__ hflag,
                                                float* __restrict__ LX, float* __restrict__ LH,
                                                int N) {
    int tid = blockIdx.x * 256 + threadIdx.x;
    int n = tid >> 5;
    int f = tid & 31;
    if (n >= N) return;
    int beg = rowptr[n], end = rowptr[n + 1];
    float acc = 0.0f, accH = 0.0f;
    int fl = *hflag;
    if (fl & 1) {
        #pragma unroll 4
        for (int i = beg; i < end; ++i) {
            int2 p = epair[i];
            float w = __int_as_float(p.y);
            acc  += w * X[(p.x << 5) + f];
            accH += w * H0[(p.x << 5) + f];
        }
    } else {
        #pragma unroll 4
        for (int i = beg; i < end; ++i) {
            int2 p = epair[i];
            acc += __int_as_float(p.y) * X[(p.x << 5) + f];
        }
    }
    LX[(n << 5) + f] = acc;
    if (fl & 1) LH[(n << 5) + f] = accH;   // LH is logically 0 otherwise; never read then
}

// Per (node-group g of NPT nodes, out-feature j): fused LSTM cell.
// Fast path (h0==0 && c0==0, detected at runtime): F-gate dead (C = I*T),
// h/lh terms are exact zero-adds -> 3 gates x 2 input types. Bit-identical.
__global__ __launch_bounds__(256) void k_gates(
    const float* __restrict__ X, const float* __restrict__ LX,
    const float* __restrict__ H0, const float* __restrict__ LH,
    const float* __restrict__ C0,
    const float* __restrict__ Wx, const float* __restrict__ bx,
    const float* __restrict__ Wh, const float* __restrict__ bh,
    const float* __restrict__ wc, const float* __restrict__ b,
    const int* __restrict__ flag,
    float* __restrict__ outH, float* __restrict__ outC, int N) {
    int tid = blockIdx.x * 256 + threadIdx.x;
    int g = tid >> 5;           // node group
    int j = tid & 31;           // output feature
    int n0 = g * NPT;
    if (n0 >= N) return;
    int cnt = min(NPT, N - n0);
    int f2 = *flag;

    if (f2 == 0) {
        // ---- fast path: h0 == 0 and c0 == 0 ----
        float xk[NPT], lxk[NPT];
        #pragma unroll
        for (int i = 0; i < NPT; ++i) { xk[i] = 0.0f; lxk[i] = 0.0f; }
        for (int i = 0; i < cnt; ++i) {
            int base = (n0 + i) << 5;
            xk[i]  = X[base + j];
            lxk[i] = LX[base + j];
        }
        // gates: 0=I, 2=T, 3=O  (gate 1 = F is dead since c0 == 0)
        float p0[NPT], p2[NPT], p3[NPT];
        float b0 = bx[0 * HID + j] + bh[0 * HID + j] + b[0 * HID + j];
        float b2 = bx[2 * HID + j] + bh[2 * HID + j] + b[2 * HID + j];
        float b3 = bx[3 * HID + j] + bh[3 * HID + j] + b[3 * HID + j];
        #pragma unroll
        for (int i = 0; i < NPT; ++i) { p0[i] = b0; p2[i] = b2; p3[i] = b3; }

        #pragma unroll 4
        for (int k = 0; k < HID; ++k) {
            int row = k * HID + j;
            float w00 = Wx[0 * 2048 + row], w01 = Wx[0 * 2048 + 1024 + row];
            float w20 = Wx[2 * 2048 + row], w21 = Wx[2 * 2048 + 1024 + row];
            float w30 = Wx[3 * 2048 + row], w31 = Wx[3 * 2048 + 1024 + row];
            #pragma unroll
            for (int i = 0; i < NPT; ++i) {
                float xv  = __shfl(xk[i],  k, 32);
                float lxv = __shfl(lxk[i], k, 32);
                p0[i] += xv * w00 + lxv * w01;
                p2[i] += xv * w20 + lxv * w21;
                p3[i] += xv * w30 + lxv * w31;
            }
        }

        float wc2 = wc[2 * HID + j];
        for (int i = 0; i < cnt; ++i) {
            int base = (n0 + i) << 5;
            float I = sigmoidf_(p0[i]);
            float T = tanhf(p2[i]);
            float C = I * T;
            float O = sigmoidf_(p3[i] + wc2 * C);
            outH[base + j] = O * tanhf(C);
            outC[base + j] = C;
        }
        return;
    }

    // ---- general path ----
    float xk[NPT], lxk[NPT], hk[NPT], lhk[NPT];
    #pragma unroll
    for (int i = 0; i < NPT; ++i) { xk[i] = 0.0f; lxk[i] = 0.0f; hk[i] = 0.0f; lhk[i] = 0.0f; }
    for (int i = 0; i < cnt; ++i) {
        int base = (n0 + i) << 5;
        xk[i]  = X[base + j];
        lxk[i] = LX[base + j];
        hk[i]  = H0[base + j];
        lhk[i] = (f2 & 1) ? LH[base + j] : 0.0f;   // LH only valid if h0 nonzero
    }

    float pre[4][NPT];
    #pragma unroll
    for (int gt = 0; gt < 4; ++gt) {
        float bb = bx[gt * HID + j] + bh[gt * HID + j] + b[gt * HID + j];
        #pragma unroll
        for (int i = 0; i < NPT; ++i) pre[gt][i] = bb;
    }

    #pragma unroll 2
    for (int k = 0; k < HID; ++k) {
        float w0[4], w1[4], w2[4], w3[4];
        int row = k * HID + j;
        #pragma unroll
        for (int gt = 0; gt < 4; ++gt) {
            w0[gt] = Wx[gt * 2048 + row];
            w1[gt] = Wx[gt * 2048 + 1024 + row];
            w2[gt] = Wh[gt * 2048 + row];
            w3[gt] = Wh[gt * 2048 + 1024 + row];
        }
        #pragma unroll
        for (int i = 0; i < NPT; ++i) {
            float xv  = __shfl(xk[i],  k, 32);
            float lxv = __shfl(lxk[i], k, 32);
            float hv  = __shfl(hk[i],  k, 32);
            float lhv = __shfl(lhk[i], k, 32);
            #pragma unroll
            for (int gt = 0; gt < 4; ++gt)
                pre[gt][i] += xv * w0[gt] + lxv * w1[gt] + hv * w2[gt] + lhv * w3[gt];
        }
    }

    float wc0 = wc[0 * HID + j], wc1 = wc[1 * HID + j], wc2 = wc[2 * HID + j];
    for (int i = 0; i < cnt; ++i) {
        int base = (n0 + i) << 5;
        float c0v = C0[base + j];
        float I  = sigmoidf_(pre[0][i] + wc0 * c0v);
        float Fg = sigmoidf_(pre[1][i] + wc1 * c0v);
        float T  = tanhf(pre[2][i]);
        float C  = Fg * c0v + I * T;
        float O  = sigmoidf_(pre[3][i] + wc2 * C);
        float H  = O * tanhf(C);
        outH[base + j] = H;
        outC[base + j] = C;
    }
}

// h[n,t] = b_lin[t] + sum_k relu(H[n,k]) * W_lin[k,t]
__global__ void k_head(const float* __restrict__ H, const float* __restrict__ Wl,
                       const float* __restrict__ bl, float* __restrict__ hout, int N) {
    int tid = blockIdx.x * 256 + threadIdx.x;
    int n = tid / HOR;
    int t = tid - n * HOR;
    if (n >= N) return;
    float acc = bl[t];
    #pragma unroll
    for (int k = 0; k < HID; ++k) {
        float v = H[(n << 5) + k];
        acc += fmaxf(v, 0.0f) * Wl[k * HOR + t];
    }
    hout[n * HOR + t] = acc;
}

extern "C" void kernel_launch(void* const* d_in, const int* in_sizes, int n_in,
                              void* d_out, int out_size, void* d_ws, size_t ws_size,
                              hipStream_t stream) {
    const float* x  = (const float*)d_in[0];
    const int*   ei = (const int*)d_in[1];
    const float* ew = (const float*)d_in[2];
    const float* Wx = (const float*)d_in[3];
    const float* bx = (const float*)d_in[4];
    const float* Wh = (const float*)d_in[5];
    const float* bh = (const float*)d_in[6];
    const float* wc = (const float*)d_in[7];
    const float* b  = (const float*)d_in[8];
    const float* Wl = (const float*)d_in[9];
    const float* bl = (const float*)d_in[10];
    const float* h0 = (const float*)d_in[11];
    const float* c0 = (const float*)d_in[12];

    int N = in_sizes[0] / HID;      // x is (N,1,32)
    int E = in_sizes[2];            // edge_weight is (E,)
    const int* src = ei;
    const int* dst = ei + E;

    int ng = (N + 255) >> 8;        // 196 high-byte groups (N <= 65536 required)
    int chunk = (E + NB - 1) / NB;  // edges per hist/scatter block

    // workspace (4-byte units):
    // [tmpD 2E] [tmpS 2E (aliased by epair)] [LX N*32] [LH N*32] [rowptr N+1]
    // [hist 2*ng*NB] [off 2*ng*NB] [binTot 512] [baseS 257] [baseD 257] [dinv N] [flag 1]
    // tmpS is dead after k_degsum, so k_scatter2 may overwrite it with epair.
    int* wsi = (int*)d_ws;
    int2*  tmpD   = (int2*)wsi;
    int2*  tmpS   = (int2*)(wsi + 2 * (size_t)E);
    int2*  epair  = tmpS;                                // alias (see above)
    float* LX     = (float*)(wsi + 4 * (size_t)E);
    float* LH     = LX + (size_t)N * HID;
    int*   rowptr = (int*)(LH + (size_t)N * HID);
    int*   hist   = rowptr + (N + 1);
    int*   off    = hist + 2 * (size_t)ng * NB;
    int*   binTot = off + 2 * (size_t)ng * NB;
    int*   baseS  = binTot + 512;
    int*   baseD  = baseS + 257;
    float* dinv   = (float*)(baseD + 257);
    int*   flag   = (int*)(dinv + N);

    float* hOut = (float*)d_out;            // (N,12)
    float* HOut = hOut + (size_t)N * HOR;   // (N,32)
    float* COut = HOut + (size_t)N * HID;   // (N,32)

    hipMemsetAsync(flag, 0, sizeof(int), stream);

    k_hist<<<NB, 256, 0, stream>>>(src, dst, hist, E, chunk, ng);
    k_binscan<<<2 * ng, 256, 0, stream>>>(hist, off, binTot, ng);
    k_binbase<<<1, 512, 0, stream>>>(binTot, baseS, baseD, rowptr, E, ng, N);
    k_scatter<<<NB, 256, 0, stream>>>(src, dst, ew, off, baseS, baseD, tmpS, tmpD, E, chunk, ng);
    k_degsum<<<ng, 256, 0, stream>>>(tmpS, baseS, dinv, N);
    k_flags<<<(N * HID + 255) / 256, 256, 0, stream>>>(h0, c0, flag, N * HID);
    k_scatter2<<<ng, 256, 0, stream>>>(tmpD, baseD, dinv, rowptr, epair, N);

    k_gather<<<(N * HID + 255) / 256, 256, 0, stream>>>(rowptr, epair, x, h0, flag, LX, LH, N);

    int gThreads = ((N + NPT - 1) / NPT) * 32;
    k_gates<<<(gThreads + 255) / 256, 256, 0, stream>>>(x, LX, h0, LH, c0,
                                                        Wx, bx, Wh, bh, wc, b, flag,
                                                        HOut, COut, N);

    k_head<<<(N * HOR + 255) / 256, 256, 0, stream>>>(HOut, Wl, bl, hOut, N);
}

// Round 5
// 275.458 us; speedup vs baseline: 1.7221x; 1.0106x over previous
//
#include <hip/hip_runtime.h>
#include <math.h>

#define HID 32
#define HOR 12
#define NB  256   // first-level blocks; k_binscan's 256 threads own one block each
#define GSH 6     // group shift: 64 nodes per group
#define GW  64    // group width
#define NPT 4     // nodes per thread in k_gates

__device__ __forceinline__ float sigmoidf_(float x) { return 1.0f / (1.0f + expf(-x)); }

// ---------------------------------------------------------------------------
// MSD bucket sort by node id (node < 65536 required: N = 50000).
// Level 1: node>>6 (782 groups) via per-block LDS histograms + global scatter.
// Level 2: node&63, entirely inside one block per group (782 blocks -> 3/CU).
// All atomics are LDS atomics; every global write is a plain store.
// Table layouts chosen so latency-critical READS are coalesced:
//   hist[bin*NB + block]  (scattered write in k_hist, coalesced read in binscan)
//   off [block*2ng + bin] (scattered write in binscan, coalesced read in scatter)
// ---------------------------------------------------------------------------

// per-block histograms of src>>6 and dst>>6
__global__ __launch_bounds__(1024) void k_hist(const int* __restrict__ src,
                                               const int* __restrict__ dst,
                                               int* __restrict__ hist,
                                               int E, int chunk, int ng) {
    __shared__ int hS[1024], hD[1024];
    int t = threadIdx.x, b = blockIdx.x;
    for (int i = t; i < ng; i += 1024) { hS[i] = 0; hD[i] = 0; }
    __syncthreads();
    int beg = b * chunk, end = min(E, beg + chunk);
    for (int e = beg + t; e < end; e += 1024) {
        atomicAdd(&hS[src[e] >> GSH], 1);
        atomicAdd(&hD[dst[e] >> GSH], 1);
    }
    __syncthreads();
    for (int i = t; i < ng; i += 1024) {
        hist[(size_t)i * NB + b] = hS[i];               // S bins: [0, ng)
        hist[((size_t)ng + i) * NB + b] = hD[i];        // D bins: [ng, 2ng)
    }
}

// per-bin exclusive scan across the NB blocks (one block per bin)
__global__ __launch_bounds__(256) void k_binscan(const int* __restrict__ hist,
                                                 int* __restrict__ off,
                                                 int* __restrict__ binTot, int ng2) {
    __shared__ int s[256];
    int b2 = blockIdx.x, t = threadIdx.x;
    int v = hist[(size_t)b2 * NB + t];                  // coalesced
    s[t] = v;
    __syncthreads();
    for (int o = 1; o < 256; o <<= 1) {
        int x = (t >= o) ? s[t - o] : 0;
        __syncthreads();
        s[t] += x;
        __syncthreads();
    }
    off[(size_t)t * ng2 + b2] = s[t] - v;               // block-major (scattered)
    if (t == 255) binTot[b2] = s[255];
}

// 2 blocks x 1024: block 0 scans S bin totals, block 1 scans D bin totals.
__global__ __launch_bounds__(1024) void k_binbase(const int* __restrict__ binTot,
                                                  int* __restrict__ baseS, int* __restrict__ baseD,
                                                  int* __restrict__ rowptr,
                                                  int E, int ng, int N) {
    __shared__ int buf[1024];
    int t = threadIdx.x;
    int isD = blockIdx.x;
    int sum = (t < ng) ? binTot[isD * ng + t] : 0;
    buf[t] = sum;
    __syncthreads();
    for (int o = 1; o < 1024; o <<= 1) {
        int v = (t >= o) ? buf[t - o] : 0;
        __syncthreads();
        buf[t] += v;
        __syncthreads();
    }
    int base = buf[t] - sum;                            // exclusive
    int* B = isD ? baseD : baseS;
    if (t < ng) B[t] = base;
    if (t == 0) { B[ng] = E; if (!isD) rowptr[N] = E; }
}

// scatter edges into 64-wide groups (both keyings) using LDS cursors.
__global__ __launch_bounds__(1024) void k_scatter(const int* __restrict__ src,
                                                  const int* __restrict__ dst,
                                                  const float* __restrict__ w,
                                                  const int* __restrict__ off,
                                                  const int* __restrict__ baseS,
                                                  const int* __restrict__ baseD,
                                                  int2* __restrict__ tmpS, int2* __restrict__ tmpD,
                                                  int E, int chunk, int ng) {
    __shared__ int cS[1024], cD[1024];
    int t = threadIdx.x, b = blockIdx.x;
    int ng2 = 2 * ng;
    for (int i = t; i < ng; i += 1024) {
        cS[i] = off[(size_t)b * ng2 + i] + baseS[i];          // coalesced
        cD[i] = off[(size_t)b * ng2 + ng + i] + baseD[i];
    }
    __syncthreads();
    int beg = b * chunk, end = min(E, beg + chunk);
    for (int e = beg + t; e < end; e += 1024) {
        int s = src[e], d = dst[e];
        int wb = __float_as_int(w[e]);
        int pS = atomicAdd(&cS[s >> GSH], 1);
        tmpS[pS] = make_int2(s, wb);
        int pD = atomicAdd(&cD[d >> GSH], 1);
        tmpD[pD] = make_int2(s | ((d & (GW - 1)) << 16), wb); // src fits 16 bits
    }
}

// per src-group: LDS float histogram over low 6 bits -> dinv (no global atomics)
__global__ __launch_bounds__(256) void k_degsum(const int2* __restrict__ tmpS,
                                                const int* __restrict__ baseS,
                                                float* __restrict__ dinv, int N) {
    __shared__ float h[GW];
    int g = blockIdx.x, t = threadIdx.x;
    if (t < GW) h[t] = 0.0f;
    __syncthreads();
    int beg = baseS[g], end = baseS[g + 1];
    for (int i = beg + t; i < end; i += 256) {
        int2 p = tmpS[i];
        atomicAdd(&h[p.x & (GW - 1)], __int_as_float(p.y));
    }
    __syncthreads();
    int n = (g << GSH) + t;
    if (t < GW && n < N) { float s = h[t]; dinv[n] = (s > 0.0f) ? rsqrtf(s) : 0.0f; }
}

// per dst-group: low-bits count + scan -> rowptr; then bin edges to exact dst,
// computing nw now that dinv exists. Within-dst order is arbitrary (sum).
__global__ __launch_bounds__(256) void k_scatter2(const int2* __restrict__ tmpD,
                                                  const int* __restrict__ baseD,
                                                  const float* __restrict__ dinv,
                                                  int* __restrict__ rowptr,
                                                  int2* __restrict__ epair, int N) {
    __shared__ int h[GW], cur[GW];
    int g = blockIdx.x, t = threadIdx.x;
    if (t < GW) h[t] = 0;
    __syncthreads();
    int beg = baseD[g], end = baseD[g + 1];
    for (int i = beg + t; i < end; i += 256) atomicAdd(&h[(tmpD[i].x >> 16) & (GW - 1)], 1);
    __syncthreads();
    int v = (t < GW) ? h[t] : 0;
    for (int o = 1; o < GW; o <<= 1) {
        int x = (t < GW && t >= o) ? h[t - o] : 0;
        __syncthreads();
        if (t < GW && t >= o) h[t] += x;
        __syncthreads();
    }
    if (t < GW) {
        int excl = h[t] - v;
        int n = (g << GSH) + t;
        if (n < N) rowptr[n] = beg + excl;
        cur[t] = beg + excl;
    }
    __syncthreads();
    for (int i = beg + t; i < end; i += 256) {
        int2 p = tmpD[i];
        int low = (p.x >> 16) & (GW - 1);
        int s = p.x & 0xFFFF;
        int pos = atomicAdd(&cur[low], 1);
        float nw = -dinv[s] * __int_as_float(p.y) * dinv[(g << GSH) + low];
        epair[pos] = make_int2(s, __float_as_int(nw));
    }
}

// flag bit0 = any h0 nonzero, bit1 = any c0 nonzero
__global__ void k_flags(const float* __restrict__ h0, const float* __restrict__ c0,
                        int* __restrict__ flag, int total) {
    int i = blockIdx.x * 256 + threadIdx.x;
    float a = (i < total) ? h0[i] : 0.0f;
    float c = (i < total) ? c0[i] : 0.0f;
    unsigned long long ba = __ballot(a != 0.0f);
    unsigned long long bc = __ballot(c != 0.0f);
    if ((threadIdx.x & 63) == 0) {
        int m = (ba ? 1 : 0) | (bc ? 2 : 0);
        if (m) atomicOr(flag, m);
    }
}

// per dst node (32 lanes = 32 feats): accumulate LX (and LH if h0 nonzero)
__global__ __launch_bounds__(256) void k_gather(const int* __restrict__ rowptr,
                                                const int2* __restrict__ epair,
                                                const float* __restrict__ X,
                                                const float* __restrict__ H0,
                                                const int* __restrict__ hflag,
                                                float* __restrict__ LX, float* __restrict__ LH,
                                                int N) {
    int tid = blockIdx.x * 256 + threadIdx.x;
    int n = tid >> 5;
    int f = tid & 31;
    if (n >= N) return;
    int beg = rowptr[n], end = rowptr[n + 1];
    float acc = 0.0f, accH = 0.0f;
    int fl = *hflag;
    if (fl & 1) {
        #pragma unroll 4
        for (int i = beg; i < end; ++i) {
            int2 p = epair[i];
            float w = __int_as_float(p.y);
            acc  += w * X[(p.x << 5) + f];
            accH += w * H0[(p.x << 5) + f];
        }
    } else {
        #pragma unroll 4
        for (int i = beg; i < end; ++i) {
            int2 p = epair[i];
            acc += __int_as_float(p.y) * X[(p.x << 5) + f];
        }
    }
    LX[(n << 5) + f] = acc;
    if (fl & 1) LH[(n << 5) + f] = accH;   // LH is logically 0 otherwise; never read then
}

// Per (node-group g of NPT nodes, out-feature j): fused LSTM cell.
// Fast path (h0==0 && c0==0, detected at runtime): F-gate dead (C = I*T),
// h/lh terms are exact zero-adds -> 3 gates x 2 input types. Bit-identical.
__global__ __launch_bounds__(256) void k_gates(
    const float* __restrict__ X, const float* __restrict__ LX,
    const float* __restrict__ H0, const float* __restrict__ LH,
    const float* __restrict__ C0,
    const float* __restrict__ Wx, const float* __restrict__ bx,
    const float* __restrict__ Wh, const float* __restrict__ bh,
    const float* __restrict__ wc, const float* __restrict__ b,
    const int* __restrict__ flag,
    float* __restrict__ outH, float* __restrict__ outC, int N) {
    int tid = blockIdx.x * 256 + threadIdx.x;
    int g = tid >> 5;           // node group
    int j = tid & 31;           // output feature
    int n0 = g * NPT;
    if (n0 >= N) return;
    int cnt = min(NPT, N - n0);
    int f2 = *flag;

    if (f2 == 0) {
        // ---- fast path: h0 == 0 and c0 == 0 ----
        float xk[NPT], lxk[NPT];
        #pragma unroll
        for (int i = 0; i < NPT; ++i) { xk[i] = 0.0f; lxk[i] = 0.0f; }
        for (int i = 0; i < cnt; ++i) {
            int base = (n0 + i) << 5;
            xk[i]  = X[base + j];
            lxk[i] = LX[base + j];
        }
        // gates: 0=I, 2=T, 3=O  (gate 1 = F is dead since c0 == 0)
        float p0[NPT], p2[NPT], p3[NPT];
        float b0 = bx[0 * HID + j] + bh[0 * HID + j] + b[0 * HID + j];
        float b2 = bx[2 * HID + j] + bh[2 * HID + j] + b[2 * HID + j];
        float b3 = bx[3 * HID + j] + bh[3 * HID + j] + b[3 * HID + j];
        #pragma unroll
        for (int i = 0; i < NPT; ++i) { p0[i] = b0; p2[i] = b2; p3[i] = b3; }

        #pragma unroll 4
        for (int k = 0; k < HID; ++k) {
            int row = k * HID + j;
            float w00 = Wx[0 * 2048 + row], w01 = Wx[0 * 2048 + 1024 + row];
            float w20 = Wx[2 * 2048 + row], w21 = Wx[2 * 2048 + 1024 + row];
            float w30 = Wx[3 * 2048 + row], w31 = Wx[3 * 2048 + 1024 + row];
            #pragma unroll
            for (int i = 0; i < NPT; ++i) {
                float xv  = __shfl(xk[i],  k, 32);
                float lxv = __shfl(lxk[i], k, 32);
                p0[i] += xv * w00 + lxv * w01;
                p2[i] += xv * w20 + lxv * w21;
                p3[i] += xv * w30 + lxv * w31;
            }
        }

        float wc2 = wc[2 * HID + j];
        for (int i = 0; i < cnt; ++i) {
            int base = (n0 + i) << 5;
            float I = sigmoidf_(p0[i]);
            float T = tanhf(p2[i]);
            float C = I * T;
            float O = sigmoidf_(p3[i] + wc2 * C);
            outH[base + j] = O * tanhf(C);
            outC[base + j] = C;
        }
        return;
    }

    // ---- general path ----
    float xk[NPT], lxk[NPT], hk[NPT], lhk[NPT];
    #pragma unroll
    for (int i = 0; i < NPT; ++i) { xk[i] = 0.0f; lxk[i] = 0.0f; hk[i] = 0.0f; lhk[i] = 0.0f; }
    for (int i = 0; i < cnt; ++i) {
        int base = (n0 + i) << 5;
        xk[i]  = X[base + j];
        lxk[i] = LX[base + j];
        hk[i]  = H0[base + j];
        lhk[i] = (f2 & 1) ? LH[base + j] : 0.0f;   // LH only valid if h0 nonzero
    }

    float pre[4][NPT];
    #pragma unroll
    for (int gt = 0; gt < 4; ++gt) {
        float bb = bx[gt * HID + j] + bh[gt * HID + j] + b[gt * HID + j];
        #pragma unroll
        for (int i = 0; i < NPT; ++i) pre[gt][i] = bb;
    }

    #pragma unroll 2
    for (int k = 0; k < HID; ++k) {
        float w0[4], w1[4], w2[4], w3[4];
        int row = k * HID + j;
        #pragma unroll
        for (int gt = 0; gt < 4; ++gt) {
            w0[gt] = Wx[gt * 2048 + row];
            w1[gt] = Wx[gt * 2048 + 1024 + row];
            w2[gt] = Wh[gt * 2048 + row];
            w3[gt] = Wh[gt * 2048 + 1024 + row];
        }
        #pragma unroll
        for (int i = 0; i < NPT; ++i) {
            float xv  = __shfl(xk[i],  k, 32);
            float lxv = __shfl(lxk[i], k, 32);
            float hv  = __shfl(hk[i],  k, 32);
            float lhv = __shfl(lhk[i], k, 32);
            #pragma unroll
            for (int gt = 0; gt < 4; ++gt)
                pre[gt][i] += xv * w0[gt] + lxv * w1[gt] + hv * w2[gt] + lhv * w3[gt];
        }
    }

    float wc0 = wc[0 * HID + j], wc1 = wc[1 * HID + j], wc2 = wc[2 * HID + j];
    for (int i = 0; i < cnt; ++i) {
        int base = (n0 + i) << 5;
        float c0v = C0[base + j];
        float I  = sigmoidf_(pre[0][i] + wc0 * c0v);
        float Fg = sigmoidf_(pre[1][i] + wc1 * c0v);
        float T  = tanhf(pre[2][i]);
        float C  = Fg * c0v + I * T;
        float O  = sigmoidf_(pre[3][i] + wc2 * C);
        float H  = O * tanhf(C);
        outH[base + j] = H;
        outC[base + j] = C;
    }
}

// h[n,t] = b_lin[t] + sum_k relu(H[n,k]) * W_lin[k,t]
__global__ void k_head(const float* __restrict__ H, const float* __restrict__ Wl,
                       const float* __restrict__ bl, float* __restrict__ hout, int N) {
    int tid = blockIdx.x * 256 + threadIdx.x;
    int n = tid / HOR;
    int t = tid - n * HOR;
    if (n >= N) return;
    float acc = bl[t];
    #pragma unroll
    for (int k = 0; k < HID; ++k) {
        float v = H[(n << 5) + k];
        acc += fmaxf(v, 0.0f) * Wl[k * HOR + t];
    }
    hout[n * HOR + t] = acc;
}

extern "C" void kernel_launch(void* const* d_in, const int* in_sizes, int n_in,
                              void* d_out, int out_size, void* d_ws, size_t ws_size,
                              hipStream_t stream) {
    const float* x  = (const float*)d_in[0];
    const int*   ei = (const int*)d_in[1];
    const float* ew = (const float*)d_in[2];
    const float* Wx = (const float*)d_in[3];
    const float* bx = (const float*)d_in[4];
    const float* Wh = (const float*)d_in[5];
    const float* bh = (const float*)d_in[6];
    const float* wc = (const float*)d_in[7];
    const float* b  = (const float*)d_in[8];
    const float* Wl = (const float*)d_in[9];
    const float* bl = (const float*)d_in[10];
    const float* h0 = (const float*)d_in[11];
    const float* c0 = (const float*)d_in[12];

    int N = in_sizes[0] / HID;      // x is (N,1,32)
    int E = in_sizes[2];            // edge_weight is (E,)
    const int* src = ei;
    const int* dst = ei + E;

    int ng = (N + GW - 1) >> GSH;   // 782 groups (requires N <= 65536)
    int ng2 = 2 * ng;
    int chunk = (E + NB - 1) / NB;  // edges per hist/scatter block

    // workspace (4-byte units):
    // [tmpD 2E] [tmpS 2E (aliased by epair)] [LX N*32] [LH N*32] [rowptr N+1]
    // [hist 2*ng*NB] [off 2*ng*NB] [binTot 2048] [baseS ng+1] [baseD ng+1] [dinv N] [flag 1]
    // tmpS is dead after k_degsum, so k_scatter2 may overwrite it with epair.
    int* wsi = (int*)d_ws;
    int2*  tmpD   = (int2*)wsi;
    int2*  tmpS   = (int2*)(wsi + 2 * (size_t)E);
    int2*  epair  = tmpS;                                // alias (see above)
    float* LX     = (float*)(wsi + 4 * (size_t)E);
    float* LH     = LX + (size_t)N * HID;
    int*   rowptr = (int*)(LH + (size_t)N * HID);
    int*   hist   = rowptr + (N + 1);
    int*   off    = hist + (size_t)ng2 * NB;
    int*   binTot = off + (size_t)ng2 * NB;
    int*   baseS  = binTot + 2048;
    int*   baseD  = baseS + (ng + 1);
    float* dinv   = (float*)(baseD + (ng + 1));
    int*   flag   = (int*)(dinv + N);

    float* hOut = (float*)d_out;            // (N,12)
    float* HOut = hOut + (size_t)N * HOR;   // (N,32)
    float* COut = HOut + (size_t)N * HID;   // (N,32)

    hipMemsetAsync(flag, 0, sizeof(int), stream);

    k_hist<<<NB, 1024, 0, stream>>>(src, dst, hist, E, chunk, ng);
    k_binscan<<<ng2, 256, 0, stream>>>(hist, off, binTot, ng2);
    k_binbase<<<2, 1024, 0, stream>>>(binTot, baseS, baseD, rowptr, E, ng, N);
    k_scatter<<<NB, 1024, 0, stream>>>(src, dst, ew, off, baseS, baseD, tmpS, tmpD, E, chunk, ng);
    k_degsum<<<ng, 256, 0, stream>>>(tmpS, baseS, dinv, N);
    k_flags<<<(N * HID + 255) / 256, 256, 0, stream>>>(h0, c0, flag, N * HID);
    k_scatter2<<<ng, 256, 0, stream>>>(tmpD, baseD, dinv, rowptr, epair, N);

    k_gather<<<(N * HID + 255) / 256, 256, 0, stream>>>(rowptr, epair, x, h0, flag, LX, LH, N);

    int gThreads = ((N + NPT - 1) / NPT) * 32;
    k_gates<<<(gThreads + 255) / 256, 256, 0, stream>>>(x, LX, h0, LH, c0,
                                                        Wx, bx, Wh, bh, wc, b, flag,
                                                        HOut, COut, N);

    k_head<<<(N * HOR + 255) / 256, 256, 0, stream>>>(HOut, Wl, bl, hOut, N);
}